// Round 6
// baseline (467.494 us; speedup 1.0000x reference)
//
#include <hip/hip_runtime.h>
#include <hip/hip_bf16.h>
#include <stdint.h>

// MHA forward: B=4, S=2048, D=512, H=8, HD=64. f32 in/out, bf16 MFMA internally.
// out0 = out [B,S,D] f32, out1 = attn [B,H,S,S] f32 (concatenated in d_out).

typedef __attribute__((ext_vector_type(8))) short bf16x8;
typedef __attribute__((ext_vector_type(4))) short bf16x4;
typedef __attribute__((ext_vector_type(4))) float f32x4;

#define MFMA16(a, b, c) __builtin_amdgcn_mfma_f32_16x16x32_bf16((a), (b), (c), 0, 0, 0)

__device__ __forceinline__ unsigned short f2bf(float f) {
  unsigned u = __float_as_uint(f);
  u += 0x7FFFu + ((u >> 16) & 1u);   // RNE
  return (unsigned short)(u >> 16);
}
__device__ __forceinline__ float bf2f(unsigned short u) {
  return __uint_as_float(((unsigned)u) << 16);
}

// ---------------------------------------------------------------------------
// Kernel 1: fused QKV projection. z = 0,1,2 -> q,k,v.
// q,k written as [B,H,S,HD] bf16; v written transposed [B,H,HD,S] bf16.
// ---------------------------------------------------------------------------
__global__ __launch_bounds__(256) void k_proj_qkv(
    const float* __restrict__ q_in, const float* __restrict__ k_in,
    const float* __restrict__ v_in,
    const float* __restrict__ Wq, const float* __restrict__ bq,
    const float* __restrict__ Wk, const float* __restrict__ bk,
    const float* __restrict__ Wv, const float* __restrict__ bv,
    unsigned short* __restrict__ q_ws, unsigned short* __restrict__ k_ws,
    unsigned short* __restrict__ vt_ws)
{
  const int z = blockIdx.z;
  const float* X    = (z == 0) ? q_in : (z == 1) ? k_in : v_in;
  const float* W    = (z == 0) ? Wq   : (z == 1) ? Wk   : Wv;
  const float* bias = (z == 0) ? bq   : (z == 1) ? bk   : bv;
  unsigned short* out = (z == 0) ? q_ws : (z == 1) ? k_ws : vt_ws;

  __shared__ unsigned short As[128][72];
  __shared__ unsigned short Bs[128][72];

  const int t = threadIdx.x;
  const int lane = t & 63;
  const int w = t >> 6;
  const int wr = w >> 1, wc = w & 1;
  const int mbase = blockIdx.x * 128;
  const int nbase = blockIdx.y * 128;

  f32x4 acc[4][4] = {};

  for (int kb = 0; kb < 512; kb += 64) {
    __syncthreads();
#pragma unroll
    for (int i = 0; i < 4; ++i) {
      int chunk = i * 256 + t;
      int row = chunk >> 3;
      int c8 = (chunk & 7) * 8;
      const float* ga = X + (size_t)(mbase + row) * 512 + kb + c8;
      float4 a0 = *(const float4*)ga;
      float4 a1 = *(const float4*)(ga + 4);
      bf16x8 pa;
      pa[0] = (short)f2bf(a0.x); pa[1] = (short)f2bf(a0.y);
      pa[2] = (short)f2bf(a0.z); pa[3] = (short)f2bf(a0.w);
      pa[4] = (short)f2bf(a1.x); pa[5] = (short)f2bf(a1.y);
      pa[6] = (short)f2bf(a1.z); pa[7] = (short)f2bf(a1.w);
      *(bf16x8*)&As[row][c8] = pa;
      const float* gb = W + (size_t)(nbase + row) * 512 + kb + c8;
      float4 b0 = *(const float4*)gb;
      float4 b1 = *(const float4*)(gb + 4);
      bf16x8 pb;
      pb[0] = (short)f2bf(b0.x); pb[1] = (short)f2bf(b0.y);
      pb[2] = (short)f2bf(b0.z); pb[3] = (short)f2bf(b0.w);
      pb[4] = (short)f2bf(b1.x); pb[5] = (short)f2bf(b1.y);
      pb[6] = (short)f2bf(b1.z); pb[7] = (short)f2bf(b1.w);
      *(bf16x8*)&Bs[row][c8] = pb;
    }
    __syncthreads();
#pragma unroll
    for (int kk = 0; kk < 64; kk += 32) {
      bf16x8 af[4], bfr[4];
#pragma unroll
      for (int mi = 0; mi < 4; ++mi)
        af[mi] = *(const bf16x8*)&As[wr * 64 + mi * 16 + (lane & 15)][kk + (lane >> 4) * 8];
#pragma unroll
      for (int ni = 0; ni < 4; ++ni)
        bfr[ni] = *(const bf16x8*)&Bs[wc * 64 + ni * 16 + (lane & 15)][kk + (lane >> 4) * 8];
#pragma unroll
      for (int mi = 0; mi < 4; ++mi)
#pragma unroll
        for (int ni = 0; ni < 4; ++ni)
          acc[mi][ni] = MFMA16(af[mi], bfr[ni], acc[mi][ni]);
    }
  }

#pragma unroll
  for (int ni = 0; ni < 4; ++ni) {
    int n = nbase + wc * 64 + ni * 16 + (lane & 15);
    float bv_ = bias[n];
    int h = n >> 6, hd = n & 63;
#pragma unroll
    for (int mi = 0; mi < 4; ++mi) {
#pragma unroll
      for (int i = 0; i < 4; ++i) {
        int m = mbase + wr * 64 + mi * 16 + (lane >> 4) * 4 + i;
        int b_ = m >> 11, s = m & 2047;
        float val = acc[mi][ni][i] + bv_;
        size_t off;
        if (z < 2) off = ((size_t)(b_ * 8 + h) * 2048 + s) * 64 + hd;      // [B,H,S,HD]
        else       off = ((size_t)(b_ * 8 + h) * 64 + hd) * 2048 + s;      // [B,H,HD,S]
        out[off] = f2bf(val);
      }
    }
  }
}

// ---------------------------------------------------------------------------
// Kernel 2: attention. Block = (b,h) x 16 q-rows, 8 waves (512 thr).
// Wave w owns k-cols [w*256..+256). Swapped QK^T: mfma(K,Q) -> lane (lo=q,hi)
// holds 4 consecutive k for its own q row. Phases strictly separated so no
// load ever waits (via FIFO vmcnt) on a nontemporal store:
//  1 QK^T+exp (loads only) -> 2 denom -> 3 PV (loads+MFMA, normalized P)
//  -> 4 O reduce+write -> 5 attn nt stores (stores only, nothing waits).
// ---------------------------------------------------------------------------
__global__ __launch_bounds__(512) void k_attn(
    const unsigned short* __restrict__ q_ws, const unsigned short* __restrict__ k_ws,
    const unsigned short* __restrict__ vt_ws, unsigned short* __restrict__ o_ws,
    float* __restrict__ attn_out)
{
  __shared__ float o_red[8][16][68];            // per-wave O partials (+4 pad)
  __shared__ float wsum[8][16];
  __shared__ float rinv_s[16];

  const int t = threadIdx.x;
  const int lane = t & 63;
  const int w = t >> 6;            // 0..7
  const int lo = lane & 15;
  const int hi = lane >> 4;        // 0..3
  const int bh = blockIdx.y;       // 0..31
  const int qbase = blockIdx.x * 16;
  const size_t qk_base = (size_t)bh * 2048 * 64;
  const int kw = w * 256;          // wave's k range

  // Q fragments (B operand: col = q = lo, d = hi*8 + j)
  bf16x8 qf0 = *(const bf16x8*)(q_ws + qk_base + (size_t)(qbase + lo) * 64 + hi * 8);
  bf16x8 qf1 = *(const bf16x8*)(q_ws + qk_base + (size_t)(qbase + lo) * 64 + 32 + hi * 8);

  unsigned p_pk[16][2];            // packed bf16 pairs: k = tile*16 + hi*4 + (0..3), q = lo
  float srow = 0.f;                // partial row sum for q = lo

  // --- Phase 1: QK^T -> exp -> packed regs + row-sum partials ---
#pragma unroll
  for (int t2 = 0; t2 < 16; ++t2) {
    const int cb = kw + t2 * 16;
    const unsigned short* kp = k_ws + qk_base + (size_t)(cb + lo) * 64 + hi * 8;
    bf16x8 kf0 = *(const bf16x8*)kp;
    bf16x8 kf1 = *(const bf16x8*)(kp + 32);
    f32x4 c = {};
    c = MFMA16(kf0, qf0, c);
    c = MFMA16(kf1, qf1, c);
    float e0 = __expf(c[0] * 0.125f);
    float e1 = __expf(c[1] * 0.125f);
    float e2 = __expf(c[2] * 0.125f);
    float e3 = __expf(c[3] * 0.125f);
    srow += (e0 + e1) + (e2 + e3);
    p_pk[t2][0] = (unsigned)f2bf(e0) | ((unsigned)f2bf(e1) << 16);
    p_pk[t2][1] = (unsigned)f2bf(e2) | ((unsigned)f2bf(e3) << 16);
  }

  // --- Phase 2: denominator (lanes sharing lo hold partials for same q) ---
  srow += __shfl_xor(srow, 16, 64);
  srow += __shfl_xor(srow, 32, 64);
  if (hi == 0) wsum[w][lo] = srow;
  __syncthreads();
  if (t < 16) {
    float s = 0.f;
#pragma unroll
    for (int ww = 0; ww < 8; ++ww) s += wsum[ww][t];
    rinv_s[t] = 1.0f / s;
  }
  __syncthreads();

  // --- Phase 3: PV MFMA with normalized P (loads + MFMA only, no stores) ---
  f32x4 o_acc[4] = {};             // [hd-tile]: rows q = hi*4+i, col hd = hdt*16+lo
  const float rv = rinv_s[lo];
  {
#pragma unroll
    for (int tp = 0; tp < 8; ++tp) {
      const int cb = kw + tp * 32;
      unsigned a0 = p_pk[2 * tp][0], a1 = p_pk[2 * tp][1];
      unsigned b0 = p_pk[2 * tp + 1][0], b1 = p_pk[2 * tp + 1][1];
      // PV A-operand: normalized bf16, slots 0..3 = t2a, 4..7 = t2b
      bf16x8 pa8;
      pa8[0] = (short)f2bf(bf2f((unsigned short)(a0 & 0xffffu)) * rv);
      pa8[1] = (short)f2bf(bf2f((unsigned short)(a0 >> 16)) * rv);
      pa8[2] = (short)f2bf(bf2f((unsigned short)(a1 & 0xffffu)) * rv);
      pa8[3] = (short)f2bf(bf2f((unsigned short)(a1 >> 16)) * rv);
      pa8[4] = (short)f2bf(bf2f((unsigned short)(b0 & 0xffffu)) * rv);
      pa8[5] = (short)f2bf(bf2f((unsigned short)(b0 >> 16)) * rv);
      pa8[6] = (short)f2bf(bf2f((unsigned short)(b1 & 0xffffu)) * rv);
      pa8[7] = (short)f2bf(bf2f((unsigned short)(b1 >> 16)) * rv);
#pragma unroll
      for (int hdt = 0; hdt < 4; ++hdt) {
        const unsigned short* vp = vt_ws +
            (size_t)(bh * 64 + hdt * 16 + lo) * 2048 + cb + hi * 4;
        bf16x4 v4a = *(const bf16x4*)vp;
        bf16x4 v4b = *(const bf16x4*)(vp + 16);
        bf16x8 vb8;
        vb8[0] = v4a[0]; vb8[1] = v4a[1]; vb8[2] = v4a[2]; vb8[3] = v4a[3];
        vb8[4] = v4b[0]; vb8[5] = v4b[1]; vb8[6] = v4b[2]; vb8[7] = v4b[3];
        o_acc[hdt] = MFMA16(pa8, vb8, o_acc[hdt]);
      }
    }
  }

  // --- Phase 4: O reduce across waves + write (already normalized) ---
#pragma unroll
  for (int hdt = 0; hdt < 4; ++hdt)
#pragma unroll
    for (int i = 0; i < 4; ++i)
      o_red[w][hi * 4 + i][hdt * 16 + lo] = o_acc[hdt][i];
  __syncthreads();
  {
    const int b_ = bh >> 3, h = bh & 7;
#pragma unroll
    for (int e = 0; e < 2; ++e) {
      int idx = t + e * 512;       // 0..1023 over [16 q][64 hd]
      int q = idx >> 6, hd = idx & 63;
      float s = 0.f;
#pragma unroll
      for (int ww = 0; ww < 8; ++ww) s += o_red[ww][q][hd];
      o_ws[((size_t)(b_ * 2048) + qbase + q) * 512 + h * 64 + hd] = f2bf(s);
    }
  }

  // --- Phase 5: attn nt stores from registers (stores only; tail) ---
  {
    float* ao = attn_out + (size_t)bh * 2048 * 2048 +
                (size_t)(qbase + lo) * 2048 + kw + hi * 4;
#pragma unroll
    for (int t2 = 0; t2 < 16; ++t2) {
      unsigned u0 = p_pk[t2][0], u1 = p_pk[t2][1];
      f32x4 s;
      s[0] = bf2f((unsigned short)(u0 & 0xffffu)) * rv;
      s[1] = bf2f((unsigned short)(u0 >> 16)) * rv;
      s[2] = bf2f((unsigned short)(u1 & 0xffffu)) * rv;
      s[3] = bf2f((unsigned short)(u1 >> 16)) * rv;
      __builtin_nontemporal_store(s, (f32x4*)(ao + t2 * 16));
    }
  }
}

// ---------------------------------------------------------------------------
// Kernel 3: output projection, f32 out.
// ---------------------------------------------------------------------------
__global__ __launch_bounds__(256) void k_proj_out(
    const unsigned short* __restrict__ Ao, const float* __restrict__ Wo,
    const float* __restrict__ bo, float* __restrict__ outp)
{
  __shared__ unsigned short As[128][72];
  __shared__ unsigned short Bs[128][72];

  const int t = threadIdx.x;
  const int lane = t & 63;
  const int w = t >> 6;
  const int wr = w >> 1, wc = w & 1;
  const int mbase = blockIdx.x * 128;
  const int nbase = blockIdx.y * 128;

  f32x4 acc[4][4] = {};

  for (int kb = 0; kb < 512; kb += 64) {
    __syncthreads();
#pragma unroll
    for (int i = 0; i < 4; ++i) {
      int chunk = i * 256 + t;
      int row = chunk >> 3;
      int c8 = (chunk & 7) * 8;
      *(bf16x8*)&As[row][c8] =
          *(const bf16x8*)(Ao + (size_t)(mbase + row) * 512 + kb + c8);
      const float* gb = Wo + (size_t)(nbase + row) * 512 + kb + c8;
      float4 b0 = *(const float4*)gb;
      float4 b1 = *(const float4*)(gb + 4);
      bf16x8 pb;
      pb[0] = (short)f2bf(b0.x); pb[1] = (short)f2bf(b0.y);
      pb[2] = (short)f2bf(b0.z); pb[3] = (short)f2bf(b0.w);
      pb[4] = (short)f2bf(b1.x); pb[5] = (short)f2bf(b1.y);
      pb[6] = (short)f2bf(b1.z); pb[7] = (short)f2bf(b1.w);
      *(bf16x8*)&Bs[row][c8] = pb;
    }
    __syncthreads();
#pragma unroll
    for (int kk = 0; kk < 64; kk += 32) {
      bf16x8 af[4], bfr[4];
#pragma unroll
      for (int mi = 0; mi < 4; ++mi)
        af[mi] = *(const bf16x8*)&As[wr * 64 + mi * 16 + (lane & 15)][kk + (lane >> 4) * 8];
#pragma unroll
      for (int ni = 0; ni < 4; ++ni)
        bfr[ni] = *(const bf16x8*)&Bs[wc * 64 + ni * 16 + (lane & 15)][kk + (lane >> 4) * 8];
#pragma unroll
      for (int mi = 0; mi < 4; ++mi)
#pragma unroll
        for (int ni = 0; ni < 4; ++ni)
          acc[mi][ni] = MFMA16(af[mi], bfr[ni], acc[mi][ni]);
    }
  }

#pragma unroll
  for (int ni = 0; ni < 4; ++ni) {
    int n = nbase + wc * 64 + ni * 16 + (lane & 15);
    float bv_ = bo[n];
#pragma unroll
    for (int mi = 0; mi < 4; ++mi) {
#pragma unroll
      for (int i = 0; i < 4; ++i) {
        int m = mbase + wr * 64 + mi * 16 + (lane >> 4) * 4 + i;
        outp[(size_t)m * 512 + n] = acc[mi][ni][i] + bv_;
      }
    }
  }
}

// ---------------------------------------------------------------------------
extern "C" void kernel_launch(void* const* d_in, const int* in_sizes, int n_in,
                              void* d_out, int out_size, void* d_ws, size_t ws_size,
                              hipStream_t stream) {
  const float* q_in = (const float*)d_in[0];
  const float* k_in = (const float*)d_in[1];
  const float* v_in = (const float*)d_in[2];
  const float* Wq = (const float*)d_in[3];
  const float* bq = (const float*)d_in[4];
  const float* Wk = (const float*)d_in[5];
  const float* bk = (const float*)d_in[6];
  const float* Wv = (const float*)d_in[7];
  const float* bv = (const float*)d_in[8];
  const float* Wo = (const float*)d_in[9];
  const float* bo = (const float*)d_in[10];

  float* out0 = (float*)d_out;                          // [B,S,D] f32
  float* attn = out0 + (size_t)4 * 2048 * 512;          // [B,H,S,S] f32

  unsigned short* ws = (unsigned short*)d_ws;
  const size_t SEG = (size_t)4 * 2048 * 512;
  unsigned short* q_ws  = ws;
  unsigned short* k_ws  = ws + SEG;
  unsigned short* vt_ws = ws + 2 * SEG;
  unsigned short* o_ws  = ws + 3 * SEG;

  dim3 g1(64, 4, 3);
  k_proj_qkv<<<g1, 256, 0, stream>>>(q_in, k_in, v_in, Wq, bq, Wk, bk, Wv, bv,
                                     q_ws, k_ws, vt_ws);
  dim3 g2(128, 32);
  k_attn<<<g2, 512, 0, stream>>>(q_ws, k_ws, vt_ws, o_ws, attn);
  dim3 g3(64, 4);
  k_proj_out<<<g3, 256, 0, stream>>>(o_ws, Wo, bo, out0);
}

// Round 7
// 439.252 us; speedup vs baseline: 1.0643x; 1.0643x over previous
//
#include <hip/hip_runtime.h>
#include <hip/hip_bf16.h>
#include <stdint.h>

// MHA forward: B=4, S=2048, D=512, H=8, HD=64. f32 in/out, bf16 MFMA internally.
// out0 = out [B,S,D] f32, out1 = attn [B,H,S,S] f32 (concatenated in d_out).

typedef __attribute__((ext_vector_type(8))) short bf16x8;
typedef __attribute__((ext_vector_type(4))) short bf16x4;
typedef __attribute__((ext_vector_type(4))) float f32x4;

#define MFMA16(a, b, c) __builtin_amdgcn_mfma_f32_16x16x32_bf16((a), (b), (c), 0, 0, 0)

__device__ __forceinline__ unsigned short f2bf(float f) {
  unsigned u = __float_as_uint(f);
  u += 0x7FFFu + ((u >> 16) & 1u);   // RNE
  return (unsigned short)(u >> 16);
}
__device__ __forceinline__ float bf2f(unsigned short u) {
  return __uint_as_float(((unsigned)u) << 16);
}

// ---------------------------------------------------------------------------
// Kernel 1: fused QKV projection. z = 0,1,2 -> q,k,v.
// q,k written as [B,H,S,HD] bf16; v written transposed [B,H,HD,S] bf16.
// ---------------------------------------------------------------------------
__global__ __launch_bounds__(256) void k_proj_qkv(
    const float* __restrict__ q_in, const float* __restrict__ k_in,
    const float* __restrict__ v_in,
    const float* __restrict__ Wq, const float* __restrict__ bq,
    const float* __restrict__ Wk, const float* __restrict__ bk,
    const float* __restrict__ Wv, const float* __restrict__ bv,
    unsigned short* __restrict__ q_ws, unsigned short* __restrict__ k_ws,
    unsigned short* __restrict__ vt_ws)
{
  const int z = blockIdx.z;
  const float* X    = (z == 0) ? q_in : (z == 1) ? k_in : v_in;
  const float* W    = (z == 0) ? Wq   : (z == 1) ? Wk   : Wv;
  const float* bias = (z == 0) ? bq   : (z == 1) ? bk   : bv;
  unsigned short* out = (z == 0) ? q_ws : (z == 1) ? k_ws : vt_ws;

  __shared__ unsigned short As[128][72];
  __shared__ unsigned short Bs[128][72];

  const int t = threadIdx.x;
  const int lane = t & 63;
  const int w = t >> 6;
  const int wr = w >> 1, wc = w & 1;
  const int mbase = blockIdx.x * 128;
  const int nbase = blockIdx.y * 128;

  f32x4 acc[4][4] = {};

  for (int kb = 0; kb < 512; kb += 64) {
    __syncthreads();
#pragma unroll
    for (int i = 0; i < 4; ++i) {
      int chunk = i * 256 + t;
      int row = chunk >> 3;
      int c8 = (chunk & 7) * 8;
      const float* ga = X + (size_t)(mbase + row) * 512 + kb + c8;
      float4 a0 = *(const float4*)ga;
      float4 a1 = *(const float4*)(ga + 4);
      bf16x8 pa;
      pa[0] = (short)f2bf(a0.x); pa[1] = (short)f2bf(a0.y);
      pa[2] = (short)f2bf(a0.z); pa[3] = (short)f2bf(a0.w);
      pa[4] = (short)f2bf(a1.x); pa[5] = (short)f2bf(a1.y);
      pa[6] = (short)f2bf(a1.z); pa[7] = (short)f2bf(a1.w);
      *(bf16x8*)&As[row][c8] = pa;
      const float* gb = W + (size_t)(nbase + row) * 512 + kb + c8;
      float4 b0 = *(const float4*)gb;
      float4 b1 = *(const float4*)(gb + 4);
      bf16x8 pb;
      pb[0] = (short)f2bf(b0.x); pb[1] = (short)f2bf(b0.y);
      pb[2] = (short)f2bf(b0.z); pb[3] = (short)f2bf(b0.w);
      pb[4] = (short)f2bf(b1.x); pb[5] = (short)f2bf(b1.y);
      pb[6] = (short)f2bf(b1.z); pb[7] = (short)f2bf(b1.w);
      *(bf16x8*)&Bs[row][c8] = pb;
    }
    __syncthreads();
#pragma unroll
    for (int kk = 0; kk < 64; kk += 32) {
      bf16x8 af[4], bfr[4];
#pragma unroll
      for (int mi = 0; mi < 4; ++mi)
        af[mi] = *(const bf16x8*)&As[wr * 64 + mi * 16 + (lane & 15)][kk + (lane >> 4) * 8];
#pragma unroll
      for (int ni = 0; ni < 4; ++ni)
        bfr[ni] = *(const bf16x8*)&Bs[wc * 64 + ni * 16 + (lane & 15)][kk + (lane >> 4) * 8];
#pragma unroll
      for (int mi = 0; mi < 4; ++mi)
#pragma unroll
        for (int ni = 0; ni < 4; ++ni)
          acc[mi][ni] = MFMA16(af[mi], bfr[ni], acc[mi][ni]);
    }
  }

#pragma unroll
  for (int ni = 0; ni < 4; ++ni) {
    int n = nbase + wc * 64 + ni * 16 + (lane & 15);
    float bv_ = bias[n];
    int h = n >> 6, hd = n & 63;
#pragma unroll
    for (int mi = 0; mi < 4; ++mi) {
#pragma unroll
      for (int i = 0; i < 4; ++i) {
        int m = mbase + wr * 64 + mi * 16 + (lane >> 4) * 4 + i;
        int b_ = m >> 11, s = m & 2047;
        float val = acc[mi][ni][i] + bv_;
        size_t off;
        if (z < 2) off = ((size_t)(b_ * 8 + h) * 2048 + s) * 64 + hd;      // [B,H,S,HD]
        else       off = ((size_t)(b_ * 8 + h) * 64 + hd) * 2048 + s;      // [B,H,HD,S]
        out[off] = f2bf(val);
      }
    }
  }
}

// ---------------------------------------------------------------------------
// Kernel 2: attention. Block = (b,h) x 16 q-rows, 8 waves (512 thr).
// Wave w owns k-cols [w*256..+256). Swapped QK^T: mfma(K,Q) -> lane (lo=q,hi)
// holds 4 consecutive k for its own q row.
//  1 QK^T+exp (regs) -> 2 denom -> 3 PV (normalized P) -> 4 O reduce+write
//  -> 5 attn store via 4-round LDS transpose: dump 16 f32/lane to LDS, then
//     512 threads nt-store wave-CONTIGUOUS f32x4 runs (memset pattern).
// smem aliased: o_red (phase 4) and the transpose tile (phase 5).
// ---------------------------------------------------------------------------
__global__ __launch_bounds__(512) void k_attn(
    const unsigned short* __restrict__ q_ws, const unsigned short* __restrict__ k_ws,
    const unsigned short* __restrict__ vt_ws, unsigned short* __restrict__ o_ws,
    float* __restrict__ attn_out)
{
  __shared__ float smem[8704];     // phase4: o_red[8][16][68]; phase5: pstg[16][516]
  __shared__ float wsum[8][16];
  __shared__ float rinv_s[16];

  const int t = threadIdx.x;
  const int lane = t & 63;
  const int w = t >> 6;            // 0..7
  const int lo = lane & 15;
  const int hi = lane >> 4;        // 0..3
  const int bh = blockIdx.y;       // 0..31
  const int qbase = blockIdx.x * 16;
  const size_t qk_base = (size_t)bh * 2048 * 64;
  const int kw = w * 256;          // wave's k range

  // Q fragments (B operand: col = q = lo, d = hi*8 + j)
  bf16x8 qf0 = *(const bf16x8*)(q_ws + qk_base + (size_t)(qbase + lo) * 64 + hi * 8);
  bf16x8 qf1 = *(const bf16x8*)(q_ws + qk_base + (size_t)(qbase + lo) * 64 + 32 + hi * 8);

  unsigned p_pk[16][2];            // packed bf16 pairs: k = t2*16 + hi*4 + (0..3), q = lo
  float srow = 0.f;                // partial row sum for q = lo

  // --- Phase 1: QK^T -> exp -> packed regs + row-sum partials ---
#pragma unroll
  for (int t2 = 0; t2 < 16; ++t2) {
    const int cb = kw + t2 * 16;
    const unsigned short* kp = k_ws + qk_base + (size_t)(cb + lo) * 64 + hi * 8;
    bf16x8 kf0 = *(const bf16x8*)kp;
    bf16x8 kf1 = *(const bf16x8*)(kp + 32);
    f32x4 c = {};
    c = MFMA16(kf0, qf0, c);
    c = MFMA16(kf1, qf1, c);
    float e0 = __expf(c[0] * 0.125f);
    float e1 = __expf(c[1] * 0.125f);
    float e2 = __expf(c[2] * 0.125f);
    float e3 = __expf(c[3] * 0.125f);
    srow += (e0 + e1) + (e2 + e3);
    p_pk[t2][0] = (unsigned)f2bf(e0) | ((unsigned)f2bf(e1) << 16);
    p_pk[t2][1] = (unsigned)f2bf(e2) | ((unsigned)f2bf(e3) << 16);
  }

  // --- Phase 2: denominator (lanes sharing lo hold partials for same q) ---
  srow += __shfl_xor(srow, 16, 64);
  srow += __shfl_xor(srow, 32, 64);
  if (hi == 0) wsum[w][lo] = srow;
  __syncthreads();
  if (t < 16) {
    float s = 0.f;
#pragma unroll
    for (int ww = 0; ww < 8; ++ww) s += wsum[ww][t];
    rinv_s[t] = 1.0f / s;
  }
  __syncthreads();

  // --- Phase 3: PV MFMA with normalized P (loads + MFMA only) ---
  f32x4 o_acc[4] = {};             // [hd-tile]: rows q = hi*4+i, col hd = hdt*16+lo
  const float rv = rinv_s[lo];
  {
#pragma unroll
    for (int tp = 0; tp < 8; ++tp) {
      const int cb = kw + tp * 32;
      unsigned a0 = p_pk[2 * tp][0], a1 = p_pk[2 * tp][1];
      unsigned b0 = p_pk[2 * tp + 1][0], b1 = p_pk[2 * tp + 1][1];
      bf16x8 pa8;
      pa8[0] = (short)f2bf(bf2f((unsigned short)(a0 & 0xffffu)) * rv);
      pa8[1] = (short)f2bf(bf2f((unsigned short)(a0 >> 16)) * rv);
      pa8[2] = (short)f2bf(bf2f((unsigned short)(a1 & 0xffffu)) * rv);
      pa8[3] = (short)f2bf(bf2f((unsigned short)(a1 >> 16)) * rv);
      pa8[4] = (short)f2bf(bf2f((unsigned short)(b0 & 0xffffu)) * rv);
      pa8[5] = (short)f2bf(bf2f((unsigned short)(b0 >> 16)) * rv);
      pa8[6] = (short)f2bf(bf2f((unsigned short)(b1 & 0xffffu)) * rv);
      pa8[7] = (short)f2bf(bf2f((unsigned short)(b1 >> 16)) * rv);
#pragma unroll
      for (int hdt = 0; hdt < 4; ++hdt) {
        const unsigned short* vp = vt_ws +
            (size_t)(bh * 64 + hdt * 16 + lo) * 2048 + cb + hi * 4;
        bf16x4 v4a = *(const bf16x4*)vp;
        bf16x4 v4b = *(const bf16x4*)(vp + 16);
        bf16x8 vb8;
        vb8[0] = v4a[0]; vb8[1] = v4a[1]; vb8[2] = v4a[2]; vb8[3] = v4a[3];
        vb8[4] = v4b[0]; vb8[5] = v4b[1]; vb8[6] = v4b[2]; vb8[7] = v4b[3];
        o_acc[hdt] = MFMA16(pa8, vb8, o_acc[hdt]);
      }
    }
  }

  // --- Phase 4: O reduce across waves + write (already normalized) ---
#pragma unroll
  for (int hdt = 0; hdt < 4; ++hdt)
#pragma unroll
    for (int i = 0; i < 4; ++i)
      smem[(w * 16 + hi * 4 + i) * 68 + hdt * 16 + lo] = o_acc[hdt][i];
  __syncthreads();
  {
    const int b_ = bh >> 3, h = bh & 7;
#pragma unroll
    for (int e = 0; e < 2; ++e) {
      int idx = t + e * 512;       // 0..1023 over [16 q][64 hd]
      int q = idx >> 6, hd = idx & 63;
      float s = 0.f;
#pragma unroll
      for (int ww = 0; ww < 8; ++ww) s += smem[(ww * 16 + q) * 68 + hd];
      o_ws[((size_t)(b_ * 2048) + qbase + q) * 512 + h * 64 + hd] = f2bf(s);
    }
  }

  // --- Phase 5: attn store via LDS transpose, wave-contiguous nt f32x4 ---
  // Round cc covers, per wave w, k in [w*256 + cc*64, +64). LDS local col =
  // w*64 + (t2&3)*16 + hi*4 (+j). Coop store maps flat f32x4 index back to
  // global k = (c4>>4)*256 + cc*64 + (c4&15)*4 -> 256B contiguous runs.
  {
    float* aobase = attn_out + (size_t)bh * 2048 * 2048 + (size_t)qbase * 2048;
#pragma unroll
    for (int cc = 0; cc < 4; ++cc) {
      __syncthreads();             // prev round's LDS reads (or phase-4 reads) done
#pragma unroll
      for (int j = 0; j < 4; ++j) {
        unsigned u0 = p_pk[cc * 4 + j][0], u1 = p_pk[cc * 4 + j][1];
        f32x4 s;
        s[0] = bf2f((unsigned short)(u0 & 0xffffu)) * rv;
        s[1] = bf2f((unsigned short)(u0 >> 16)) * rv;
        s[2] = bf2f((unsigned short)(u1 & 0xffffu)) * rv;
        s[3] = bf2f((unsigned short)(u1 >> 16)) * rv;
        *(f32x4*)&smem[lo * 516 + w * 64 + j * 16 + hi * 4] = s;
      }
      __syncthreads();
#pragma unroll
      for (int i = 0; i < 4; ++i) {
        int f = t + i * 512;       // flat f32x4 index over [16 rows][128 per row]
        int row = f >> 7;
        int c4 = f & 127;
        int k = ((c4 >> 4) << 8) + cc * 64 + ((c4 & 15) << 2);
        f32x4 v = *(const f32x4*)&smem[row * 516 + (c4 << 2)];
        __builtin_nontemporal_store(v, (f32x4*)(aobase + (size_t)row * 2048 + k));
      }
    }
  }
}

// ---------------------------------------------------------------------------
// Kernel 3: output projection, f32 out.
// ---------------------------------------------------------------------------
__global__ __launch_bounds__(256) void k_proj_out(
    const unsigned short* __restrict__ Ao, const float* __restrict__ Wo,
    const float* __restrict__ bo, float* __restrict__ outp)
{
  __shared__ unsigned short As[128][72];
  __shared__ unsigned short Bs[128][72];

  const int t = threadIdx.x;
  const int lane = t & 63;
  const int w = t >> 6;
  const int wr = w >> 1, wc = w & 1;
  const int mbase = blockIdx.x * 128;
  const int nbase = blockIdx.y * 128;

  f32x4 acc[4][4] = {};

  for (int kb = 0; kb < 512; kb += 64) {
    __syncthreads();
#pragma unroll
    for (int i = 0; i < 4; ++i) {
      int chunk = i * 256 + t;
      int row = chunk >> 3;
      int c8 = (chunk & 7) * 8;
      *(bf16x8*)&As[row][c8] =
          *(const bf16x8*)(Ao + (size_t)(mbase + row) * 512 + kb + c8);
      const float* gb = Wo + (size_t)(nbase + row) * 512 + kb + c8;
      float4 b0 = *(const float4*)gb;
      float4 b1 = *(const float4*)(gb + 4);
      bf16x8 pb;
      pb[0] = (short)f2bf(b0.x); pb[1] = (short)f2bf(b0.y);
      pb[2] = (short)f2bf(b0.z); pb[3] = (short)f2bf(b0.w);
      pb[4] = (short)f2bf(b1.x); pb[5] = (short)f2bf(b1.y);
      pb[6] = (short)f2bf(b1.z); pb[7] = (short)f2bf(b1.w);
      *(bf16x8*)&Bs[row][c8] = pb;
    }
    __syncthreads();
#pragma unroll
    for (int kk = 0; kk < 64; kk += 32) {
      bf16x8 af[4], bfr[4];
#pragma unroll
      for (int mi = 0; mi < 4; ++mi)
        af[mi] = *(const bf16x8*)&As[wr * 64 + mi * 16 + (lane & 15)][kk + (lane >> 4) * 8];
#pragma unroll
      for (int ni = 0; ni < 4; ++ni)
        bfr[ni] = *(const bf16x8*)&Bs[wc * 64 + ni * 16 + (lane & 15)][kk + (lane >> 4) * 8];
#pragma unroll
      for (int mi = 0; mi < 4; ++mi)
#pragma unroll
        for (int ni = 0; ni < 4; ++ni)
          acc[mi][ni] = MFMA16(af[mi], bfr[ni], acc[mi][ni]);
    }
  }

#pragma unroll
  for (int ni = 0; ni < 4; ++ni) {
    int n = nbase + wc * 64 + ni * 16 + (lane & 15);
    float bv_ = bo[n];
#pragma unroll
    for (int mi = 0; mi < 4; ++mi) {
#pragma unroll
      for (int i = 0; i < 4; ++i) {
        int m = mbase + wr * 64 + mi * 16 + (lane >> 4) * 4 + i;
        outp[(size_t)m * 512 + n] = acc[mi][ni][i] + bv_;
      }
    }
  }
}

// ---------------------------------------------------------------------------
extern "C" void kernel_launch(void* const* d_in, const int* in_sizes, int n_in,
                              void* d_out, int out_size, void* d_ws, size_t ws_size,
                              hipStream_t stream) {
  const float* q_in = (const float*)d_in[0];
  const float* k_in = (const float*)d_in[1];
  const float* v_in = (const float*)d_in[2];
  const float* Wq = (const float*)d_in[3];
  const float* bq = (const float*)d_in[4];
  const float* Wk = (const float*)d_in[5];
  const float* bk = (const float*)d_in[6];
  const float* Wv = (const float*)d_in[7];
  const float* bv = (const float*)d_in[8];
  const float* Wo = (const float*)d_in[9];
  const float* bo = (const float*)d_in[10];

  float* out0 = (float*)d_out;                          // [B,S,D] f32
  float* attn = out0 + (size_t)4 * 2048 * 512;          // [B,H,S,S] f32

  unsigned short* ws = (unsigned short*)d_ws;
  const size_t SEG = (size_t)4 * 2048 * 512;
  unsigned short* q_ws  = ws;
  unsigned short* k_ws  = ws + SEG;
  unsigned short* vt_ws = ws + 2 * SEG;
  unsigned short* o_ws  = ws + 3 * SEG;

  dim3 g1(64, 4, 3);
  k_proj_qkv<<<g1, 256, 0, stream>>>(q_in, k_in, v_in, Wq, bq, Wk, bk, Wv, bv,
                                     q_ws, k_ws, vt_ws);
  dim3 g2(128, 32);
  k_attn<<<g2, 512, 0, stream>>>(q_ws, k_ws, vt_ws, o_ws, attn);
  dim3 g3(64, 4);
  k_proj_out<<<g3, 256, 0, stream>>>(o_ws, Wo, bo, out0);
}

// Round 8
// 401.008 us; speedup vs baseline: 1.1658x; 1.0954x over previous
//
#include <hip/hip_runtime.h>
#include <hip/hip_bf16.h>
#include <stdint.h>

// MHA forward: B=4, S=2048, D=512, H=8, HD=64. f32 in/out, bf16 MFMA internally.
// out0 = out [B,S,D] f32, out1 = attn [B,H,S,S] f32 (concatenated in d_out).

typedef __attribute__((ext_vector_type(8))) short bf16x8;
typedef __attribute__((ext_vector_type(4))) short bf16x4;
typedef __attribute__((ext_vector_type(4))) float f32x4;

#define MFMA16(a, b, c) __builtin_amdgcn_mfma_f32_16x16x32_bf16((a), (b), (c), 0, 0, 0)

__device__ __forceinline__ unsigned short f2bf(float f) {
  unsigned u = __float_as_uint(f);
  u += 0x7FFFu + ((u >> 16) & 1u);   // RNE
  return (unsigned short)(u >> 16);
}
__device__ __forceinline__ float bf2f(unsigned short u) {
  return __uint_as_float(((unsigned)u) << 16);
}

// ---------------------------------------------------------------------------
// Kernel 1: fused QKV projection. z = 0,1,2 -> q,k,v.
// q,k written as [B,H,S,HD] bf16; v written transposed [B,H,HD,S] bf16.
// ---------------------------------------------------------------------------
__global__ __launch_bounds__(256) void k_proj_qkv(
    const float* __restrict__ q_in, const float* __restrict__ k_in,
    const float* __restrict__ v_in,
    const float* __restrict__ Wq, const float* __restrict__ bq,
    const float* __restrict__ Wk, const float* __restrict__ bk,
    const float* __restrict__ Wv, const float* __restrict__ bv,
    unsigned short* __restrict__ q_ws, unsigned short* __restrict__ k_ws,
    unsigned short* __restrict__ vt_ws)
{
  const int z = blockIdx.z;
  const float* X    = (z == 0) ? q_in : (z == 1) ? k_in : v_in;
  const float* W    = (z == 0) ? Wq   : (z == 1) ? Wk   : Wv;
  const float* bias = (z == 0) ? bq   : (z == 1) ? bk   : bv;
  unsigned short* out = (z == 0) ? q_ws : (z == 1) ? k_ws : vt_ws;

  __shared__ unsigned short As[128][72];
  __shared__ unsigned short Bs[128][72];

  const int t = threadIdx.x;
  const int lane = t & 63;
  const int w = t >> 6;
  const int wr = w >> 1, wc = w & 1;
  const int mbase = blockIdx.x * 128;
  const int nbase = blockIdx.y * 128;

  f32x4 acc[4][4] = {};

  for (int kb = 0; kb < 512; kb += 64) {
    __syncthreads();
#pragma unroll
    for (int i = 0; i < 4; ++i) {
      int chunk = i * 256 + t;
      int row = chunk >> 3;
      int c8 = (chunk & 7) * 8;
      const float* ga = X + (size_t)(mbase + row) * 512 + kb + c8;
      float4 a0 = *(const float4*)ga;
      float4 a1 = *(const float4*)(ga + 4);
      bf16x8 pa;
      pa[0] = (short)f2bf(a0.x); pa[1] = (short)f2bf(a0.y);
      pa[2] = (short)f2bf(a0.z); pa[3] = (short)f2bf(a0.w);
      pa[4] = (short)f2bf(a1.x); pa[5] = (short)f2bf(a1.y);
      pa[6] = (short)f2bf(a1.z); pa[7] = (short)f2bf(a1.w);
      *(bf16x8*)&As[row][c8] = pa;
      const float* gb = W + (size_t)(nbase + row) * 512 + kb + c8;
      float4 b0 = *(const float4*)gb;
      float4 b1 = *(const float4*)(gb + 4);
      bf16x8 pb;
      pb[0] = (short)f2bf(b0.x); pb[1] = (short)f2bf(b0.y);
      pb[2] = (short)f2bf(b0.z); pb[3] = (short)f2bf(b0.w);
      pb[4] = (short)f2bf(b1.x); pb[5] = (short)f2bf(b1.y);
      pb[6] = (short)f2bf(b1.z); pb[7] = (short)f2bf(b1.w);
      *(bf16x8*)&Bs[row][c8] = pb;
    }
    __syncthreads();
#pragma unroll
    for (int kk = 0; kk < 64; kk += 32) {
      bf16x8 af[4], bfr[4];
#pragma unroll
      for (int mi = 0; mi < 4; ++mi)
        af[mi] = *(const bf16x8*)&As[wr * 64 + mi * 16 + (lane & 15)][kk + (lane >> 4) * 8];
#pragma unroll
      for (int ni = 0; ni < 4; ++ni)
        bfr[ni] = *(const bf16x8*)&Bs[wc * 64 + ni * 16 + (lane & 15)][kk + (lane >> 4) * 8];
#pragma unroll
      for (int mi = 0; mi < 4; ++mi)
#pragma unroll
        for (int ni = 0; ni < 4; ++ni)
          acc[mi][ni] = MFMA16(af[mi], bfr[ni], acc[mi][ni]);
    }
  }

#pragma unroll
  for (int ni = 0; ni < 4; ++ni) {
    int n = nbase + wc * 64 + ni * 16 + (lane & 15);
    float bv_ = bias[n];
    int h = n >> 6, hd = n & 63;
#pragma unroll
    for (int mi = 0; mi < 4; ++mi) {
#pragma unroll
      for (int i = 0; i < 4; ++i) {
        int m = mbase + wr * 64 + mi * 16 + (lane >> 4) * 4 + i;
        int b_ = m >> 11, s = m & 2047;
        float val = acc[mi][ni][i] + bv_;
        size_t off;
        if (z < 2) off = ((size_t)(b_ * 8 + h) * 2048 + s) * 64 + hd;      // [B,H,S,HD]
        else       off = ((size_t)(b_ * 8 + h) * 64 + hd) * 2048 + s;      // [B,H,HD,S]
        out[off] = f2bf(val);
      }
    }
  }
}

// ---------------------------------------------------------------------------
// Kernel 2: attention. Block = (b,h) x 16 q-rows, 8 waves (512 thr).
// Chunked canonical form: 16 chunks of 128 kv. Per chunk: cooperative
// COALESCED staging of K[128][68] and Vt[64][132] into LDS, then wave w
// computes the 16-kv tile at c*128+w*16 (QK^T A-frag + PV B-frag from LDS,
// no global scatter). PV accumulates UNNORMALIZED; O normalized at the end.
// Tail: denominator -> O reduce/write -> attn store via LDS transpose with
// wave-contiguous nontemporal f32x4 (2KB runs).
// ---------------------------------------------------------------------------
__global__ __launch_bounds__(512, 6) void k_attn(
    const unsigned short* __restrict__ q_ws, const unsigned short* __restrict__ k_ws,
    const unsigned short* __restrict__ vt_ws, unsigned short* __restrict__ o_ws,
    float* __restrict__ attn_out)
{
  // aliased arena: per-chunk staging {K shorts [0,8704), Vt shorts [8704,17152)
  // in float units [0,8576)}; later o_red floats [0,8704) / transpose [0,8256).
  __shared__ float smem[8704];
  __shared__ float wsum[8][16];
  __shared__ float rinv_s[16];

  const int t = threadIdx.x;
  const int lane = t & 63;
  const int w = t >> 6;            // 0..7
  const int lo = lane & 15;
  const int hi = lane >> 4;        // 0..3
  const int bh = blockIdx.y;       // 0..31
  const int qbase = blockIdx.x * 16;
  const size_t qk_base = (size_t)bh * 2048 * 64;

  unsigned short* Ks = (unsigned short*)smem;           // [128][68]
  unsigned short* Vt = (unsigned short*)smem + 8704;    // [64][132]

  // Q fragments (B operand: col = q = lo, d = hi*8 + j)
  bf16x8 qf0 = *(const bf16x8*)(q_ws + qk_base + (size_t)(qbase + lo) * 64 + hi * 8);
  bf16x8 qf1 = *(const bf16x8*)(q_ws + qk_base + (size_t)(qbase + lo) * 64 + 32 + hi * 8);

  unsigned p_pk[16][2];   // chunk c: kv = c*128 + w*16 + hi*4 + {0..3}, q = lo
  f32x4 o_acc[4] = {};    // [hdt]: rows q = hi*4+i, col hd = hdt*16+lo (unnorm)
  float srow = 0.f;       // partial row sum for q = lo

  for (int c = 0; c < 16; ++c) {
    // --- cooperative coalesced staging ---
    {
      const unsigned short* kg = k_ws + qk_base + (size_t)(c * 128) * 64;
#pragma unroll
      for (int i = 0; i < 2; ++i) {
        int flat = t + i * 512;              // 0..1023
        int r = flat >> 3, c8 = (flat & 7) * 8;
        *(bf16x8*)&Ks[r * 68 + c8] = *(const bf16x8*)(kg + r * 64 + c8);
      }
      const unsigned short* vg = vt_ws + (size_t)(bh * 64) * 2048 + c * 128;
#pragma unroll
      for (int i = 0; i < 2; ++i) {
        int flat = t + i * 512;
        int hd = flat >> 4, k8 = (flat & 15) * 8;
        *(bf16x8*)&Vt[hd * 132 + k8] = *(const bf16x8*)(vg + (size_t)hd * 2048 + k8);
      }
    }
    __syncthreads();

    // --- QK^T (swapped) for this wave's 16-kv tile, from LDS ---
    bf16x8 kf0 = *(const bf16x8*)&Ks[(w * 16 + lo) * 68 + hi * 8];
    bf16x8 kf1 = *(const bf16x8*)&Ks[(w * 16 + lo) * 68 + 32 + hi * 8];
    f32x4 cacc = {};
    cacc = MFMA16(kf0, qf0, cacc);
    cacc = MFMA16(kf1, qf1, cacc);
    float e0 = __expf(cacc[0] * 0.125f);
    float e1 = __expf(cacc[1] * 0.125f);
    float e2 = __expf(cacc[2] * 0.125f);
    float e3 = __expf(cacc[3] * 0.125f);
    srow += (e0 + e1) + (e2 + e3);
    unsigned w0 = (unsigned)f2bf(e0) | ((unsigned)f2bf(e1) << 16);
    unsigned w1 = (unsigned)f2bf(e2) | ((unsigned)f2bf(e3) << 16);
    p_pk[c][0] = w0;
    p_pk[c][1] = w1;

    // --- PV partial (unnormalized), V from LDS. K=32 MFMA, upper half zero ---
    bf16x8 pa8;
    pa8[0] = (short)(w0 & 0xffffu); pa8[1] = (short)(w0 >> 16);
    pa8[2] = (short)(w1 & 0xffffu); pa8[3] = (short)(w1 >> 16);
    pa8[4] = 0; pa8[5] = 0; pa8[6] = 0; pa8[7] = 0;
#pragma unroll
    for (int hdt = 0; hdt < 4; ++hdt) {
      bf16x4 v4 = *(const bf16x4*)&Vt[(hdt * 16 + lo) * 132 + w * 16 + hi * 4];
      bf16x8 vb8;
      vb8[0] = v4[0]; vb8[1] = v4[1]; vb8[2] = v4[2]; vb8[3] = v4[3];
      vb8[4] = 0; vb8[5] = 0; vb8[6] = 0; vb8[7] = 0;
      o_acc[hdt] = MFMA16(pa8, vb8, o_acc[hdt]);
    }
    __syncthreads();   // staging buffers free for next chunk
  }

  // --- denominator (lanes sharing lo hold partials for same q) ---
  srow += __shfl_xor(srow, 16, 64);
  srow += __shfl_xor(srow, 32, 64);
  if (hi == 0) wsum[w][lo] = srow;
  __syncthreads();
  if (t < 16) {
    float s = 0.f;
#pragma unroll
    for (int ww = 0; ww < 8; ++ww) s += wsum[ww][t];
    rinv_s[t] = 1.0f / s;
  }
  __syncthreads();
  const float rv = rinv_s[lo];

  // --- O reduce across waves + normalize + write ---
#pragma unroll
  for (int hdt = 0; hdt < 4; ++hdt)
#pragma unroll
    for (int i = 0; i < 4; ++i)
      smem[(w * 16 + hi * 4 + i) * 68 + hdt * 16 + lo] = o_acc[hdt][i];
  __syncthreads();
  {
    const int b_ = bh >> 3, h = bh & 7;
#pragma unroll
    for (int e = 0; e < 2; ++e) {
      int idx = t + e * 512;       // 0..1023 over [16 q][64 hd]
      int q = idx >> 6, hd = idx & 63;
      float s = 0.f;
#pragma unroll
      for (int ww = 0; ww < 8; ++ww) s += smem[(ww * 16 + q) * 68 + hd];
      o_ws[((size_t)(b_ * 2048) + qbase + q) * 512 + h * 64 + hd] =
          f2bf(s * rinv_s[q]);
    }
  }

  // --- attn store via LDS transpose, wave-contiguous nt f32x4 (2KB runs) ---
  // Round cc covers chunks c = cc*4+j; local col = j*128 + w*16 + hi*4 (+e);
  // global k = cc*512 + local col.
  {
    float* aobase = attn_out + (size_t)bh * 2048 * 2048 + (size_t)qbase * 2048;
#pragma unroll
    for (int cc = 0; cc < 4; ++cc) {
      __syncthreads();             // prior reads of smem done
#pragma unroll
      for (int j = 0; j < 4; ++j) {
        unsigned u0 = p_pk[cc * 4 + j][0], u1 = p_pk[cc * 4 + j][1];
        f32x4 s;
        s[0] = bf2f((unsigned short)(u0 & 0xffffu)) * rv;
        s[1] = bf2f((unsigned short)(u0 >> 16)) * rv;
        s[2] = bf2f((unsigned short)(u1 & 0xffffu)) * rv;
        s[3] = bf2f((unsigned short)(u1 >> 16)) * rv;
        *(f32x4*)&smem[lo * 516 + j * 128 + w * 16 + hi * 4] = s;
      }
      __syncthreads();
#pragma unroll
      for (int i = 0; i < 4; ++i) {
        int f = t + i * 512;       // flat f32x4 index over [16 rows][128/row]
        int row = f >> 7;
        int c4 = f & 127;
        f32x4 v = *(const f32x4*)&smem[row * 516 + (c4 << 2)];
        __builtin_nontemporal_store(
            v, (f32x4*)(aobase + (size_t)row * 2048 + cc * 512 + (c4 << 2)));
      }
    }
  }
}

// ---------------------------------------------------------------------------
// Kernel 3: output projection, f32 out.
// ---------------------------------------------------------------------------
__global__ __launch_bounds__(256) void k_proj_out(
    const unsigned short* __restrict__ Ao, const float* __restrict__ Wo,
    const float* __restrict__ bo, float* __restrict__ outp)
{
  __shared__ unsigned short As[128][72];
  __shared__ unsigned short Bs[128][72];

  const int t = threadIdx.x;
  const int lane = t & 63;
  const int w = t >> 6;
  const int wr = w >> 1, wc = w & 1;
  const int mbase = blockIdx.x * 128;
  const int nbase = blockIdx.y * 128;

  f32x4 acc[4][4] = {};

  for (int kb = 0; kb < 512; kb += 64) {
    __syncthreads();
#pragma unroll
    for (int i = 0; i < 4; ++i) {
      int chunk = i * 256 + t;
      int row = chunk >> 3;
      int c8 = (chunk & 7) * 8;
      *(bf16x8*)&As[row][c8] =
          *(const bf16x8*)(Ao + (size_t)(mbase + row) * 512 + kb + c8);
      const float* gb = Wo + (size_t)(nbase + row) * 512 + kb + c8;
      float4 b0 = *(const float4*)gb;
      float4 b1 = *(const float4*)(gb + 4);
      bf16x8 pb;
      pb[0] = (short)f2bf(b0.x); pb[1] = (short)f2bf(b0.y);
      pb[2] = (short)f2bf(b0.z); pb[3] = (short)f2bf(b0.w);
      pb[4] = (short)f2bf(b1.x); pb[5] = (short)f2bf(b1.y);
      pb[6] = (short)f2bf(b1.z); pb[7] = (short)f2bf(b1.w);
      *(bf16x8*)&Bs[row][c8] = pb;
    }
    __syncthreads();
#pragma unroll
    for (int kk = 0; kk < 64; kk += 32) {
      bf16x8 af[4], bfr[4];
#pragma unroll
      for (int mi = 0; mi < 4; ++mi)
        af[mi] = *(const bf16x8*)&As[wr * 64 + mi * 16 + (lane & 15)][kk + (lane >> 4) * 8];
#pragma unroll
      for (int ni = 0; ni < 4; ++ni)
        bfr[ni] = *(const bf16x8*)&Bs[wc * 64 + ni * 16 + (lane & 15)][kk + (lane >> 4) * 8];
#pragma unroll
      for (int mi = 0; mi < 4; ++mi)
#pragma unroll
        for (int ni = 0; ni < 4; ++ni)
          acc[mi][ni] = MFMA16(af[mi], bfr[ni], acc[mi][ni]);
    }
  }

#pragma unroll
  for (int ni = 0; ni < 4; ++ni) {
    int n = nbase + wc * 64 + ni * 16 + (lane & 15);
    float bv_ = bo[n];
#pragma unroll
    for (int mi = 0; mi < 4; ++mi) {
#pragma unroll
      for (int i = 0; i < 4; ++i) {
        int m = mbase + wr * 64 + mi * 16 + (lane >> 4) * 4 + i;
        outp[(size_t)m * 512 + n] = acc[mi][ni][i] + bv_;
      }
    }
  }
}

// ---------------------------------------------------------------------------
extern "C" void kernel_launch(void* const* d_in, const int* in_sizes, int n_in,
                              void* d_out, int out_size, void* d_ws, size_t ws_size,
                              hipStream_t stream) {
  const float* q_in = (const float*)d_in[0];
  const float* k_in = (const float*)d_in[1];
  const float* v_in = (const float*)d_in[2];
  const float* Wq = (const float*)d_in[3];
  const float* bq = (const float*)d_in[4];
  const float* Wk = (const float*)d_in[5];
  const float* bk = (const float*)d_in[6];
  const float* Wv = (const float*)d_in[7];
  const float* bv = (const float*)d_in[8];
  const float* Wo = (const float*)d_in[9];
  const float* bo = (const float*)d_in[10];

  float* out0 = (float*)d_out;                          // [B,S,D] f32
  float* attn = out0 + (size_t)4 * 2048 * 512;          // [B,H,S,S] f32

  unsigned short* ws = (unsigned short*)d_ws;
  const size_t SEG = (size_t)4 * 2048 * 512;
  unsigned short* q_ws  = ws;
  unsigned short* k_ws  = ws + SEG;
  unsigned short* vt_ws = ws + 2 * SEG;
  unsigned short* o_ws  = ws + 3 * SEG;

  dim3 g1(64, 4, 3);
  k_proj_qkv<<<g1, 256, 0, stream>>>(q_in, k_in, v_in, Wq, bq, Wk, bk, Wv, bv,
                                     q_ws, k_ws, vt_ws);
  dim3 g2(128, 32);
  k_attn<<<g2, 512, 0, stream>>>(q_ws, k_ws, vt_ws, o_ws, attn);
  dim3 g3(64, 4);
  k_proj_out<<<g3, 256, 0, stream>>>(o_ws, Wo, bo, out0);
}